// Round 1
// baseline (208.539 us; speedup 1.0000x reference)
//
#include <hip/hip_runtime.h>
#include <hip/hip_bf16.h>

typedef __attribute__((ext_vector_type(8))) short bf16x8;
typedef __attribute__((ext_vector_type(4))) float f32x4;

constexpr int Bb = 32, Kk = 8, Ss = 512, HS = 256;

__device__ __forceinline__ unsigned short f2bf(float f) {
  unsigned int u = __builtin_bit_cast(unsigned int, f);
  u = (u + 0x7FFFu + ((u >> 16) & 1u)) >> 16;
  return (unsigned short)u;
}

// ---- pack W[k][d][e] (fp32) -> fragment-major bf16: Wp[k][kk][nt][lane][i] =
//      W[k][kk*32 + (lane>>4)*8 + i][nt*16 + (lane&15)] ----
__global__ void pack_w(const float* __restrict__ W, unsigned short* __restrict__ Wp) {
  int idx = blockIdx.x * 256 + threadIdx.x;  // 65536 groups of 8
  int lane = idx & 63, nt = (idx >> 6) & 15, kk = (idx >> 10) & 7, k = idx >> 13;
  const float* src = W + ((size_t)k * HS + kk * 32 + ((lane >> 4) * 8)) * HS + nt * 16 + (lane & 15);
  unsigned short* dst = Wp + (size_t)idx * 8;
#pragma unroll
  for (int i = 0; i < 8; ++i) dst[i] = f2bf(src[(size_t)i * HS]);
}

// ---- column sums over S (split in 2 half-blocks to up parallelism) ----
__global__ void col_sums(const float* __restrict__ rem, const float* __restrict__ ret,
                         float* __restrict__ sum_rem2, float* __restrict__ sum_ret2) {
  int gb = blockIdx.x;  // B*(K+1)*2
  int half = gb & 1, bk = gb >> 1;
  int b = bk / (Kk + 1), k = bk % (Kk + 1);
  int t = threadIdx.x;  // 512
  int col = t & 255, sc = t >> 8;
  const float* src;
  float* dst;
  if (k == Kk) {
    src = rem + (size_t)b * Ss * HS;
    dst = sum_rem2 + ((size_t)half * Bb + b) * HS;
  } else {
    src = ret + ((size_t)b * Kk + k) * Ss * HS;
    dst = sum_ret2 + ((size_t)half * Bb * Kk + b * Kk + k) * HS;
  }
  float acc = 0.f;
  int sbase = half * 256 + sc * 128;
#pragma unroll 4
  for (int s = 0; s < 128; ++s) acc += src[(size_t)(sbase + s) * HS + col];
  __shared__ float red[512];
  red[t] = acc;
  __syncthreads();
  if (t < 256) dst[t] = red[t] + red[t + 256];
}

// ---- routing: rl = (sum_rem/S)@Wr + br ; tl_k = (sum_ret/S)@Wt + bt ; softmax(rl . tl_k) ----
__global__ void routing_kernel(const float* __restrict__ sum_rem2, const float* __restrict__ sum_ret2,
                               const float* __restrict__ Wr, const float* __restrict__ br,
                               const float* __restrict__ Wt, const float* __restrict__ bt,
                               float* __restrict__ routing) {
  int b = blockIdx.x, t = threadIdx.x;  // 256 threads
  const float* s0 = sum_rem2 + (size_t)b * HS;
  const float* s1 = sum_rem2 + ((size_t)Bb + b) * HS;
  float rl = 0.f;
  for (int e = 0; e < HS; ++e) rl += (s0[e] + s1[e]) * Wr[(size_t)e * HS + t];
  rl = rl * (1.f / Ss) + br[t];

  float tl[Kk];
#pragma unroll
  for (int k = 0; k < Kk; ++k) tl[k] = 0.f;
  const float* r0 = sum_ret2 + (size_t)(b * Kk) * HS;
  const float* r1 = sum_ret2 + ((size_t)Bb * Kk + b * Kk) * HS;
  for (int e = 0; e < HS; ++e) {
    float w = Wt[(size_t)e * HS + t];
#pragma unroll
    for (int k = 0; k < Kk; ++k) tl[k] += (r0[(size_t)k * HS + e] + r1[(size_t)k * HS + e]) * w;
  }

  __shared__ float sh[4];
  __shared__ float scores[Kk];
  for (int k = 0; k < Kk; ++k) {
    float p = rl * (tl[k] * (1.f / Ss) + bt[t]);
#pragma unroll
    for (int off = 32; off; off >>= 1) p += __shfl_down(p, off);
    if ((t & 63) == 0) sh[t >> 6] = p;
    __syncthreads();
    if (t == 0) scores[k] = sh[0] + sh[1] + sh[2] + sh[3];
    __syncthreads();
  }
  if (t == 0) {
    float mx = scores[0];
    for (int k = 1; k < Kk; ++k) mx = fmaxf(mx, scores[k]);
    float s = 0.f, ev[Kk];
    for (int k = 0; k < Kk; ++k) {
      ev[k] = expf(scores[k] - mx);
      s += ev[k];
    }
    for (int k = 0; k < Kk; ++k) routing[b * Kk + k] = ev[k] / s;
  }
}

// ---- fused experts: per block: 64 S-rows, loop k: GEMM1(relu)->H, GEMM2, weighted acc ----
__launch_bounds__(256, 1)
__global__ void experts_kernel(const float* __restrict__ ret,
                               const unsigned short* __restrict__ W1p,
                               const unsigned short* __restrict__ W2p,
                               const float* __restrict__ b1, const float* __restrict__ b2,
                               const float* __restrict__ routing, float* __restrict__ out) {
  __shared__ unsigned short A_lds[64 * 256];
  __shared__ unsigned short H_lds[64 * 256];
  int blk = blockIdx.x;
  int b = blk >> 3, st = blk & 7;
  int s0 = st * 64;
  int tid = threadIdx.x;
  int wave = tid >> 6, lane = tid & 63;
  int l15 = lane & 15, l4 = lane >> 4;
  const int nbase = wave * 4;

  float out_acc[4][4][4];
#pragma unroll
  for (int m = 0; m < 4; ++m)
#pragma unroll
    for (int n = 0; n < 4; ++n)
#pragma unroll
      for (int i = 0; i < 4; ++i) out_acc[m][n][i] = 0.f;

  const f32x4 zero4 = {0.f, 0.f, 0.f, 0.f};

  for (int k = 0; k < Kk; ++k) {
    // ---- stage A tile (64x256 fp32 -> bf16, XOR-swizzled) ----
    const float* Ab = ret + (((size_t)b * Kk + k) * Ss + s0) * HS;
#pragma unroll
    for (int i = 0; i < 16; ++i) {
      int c = tid + 256 * i;
      int row = c >> 6, c4 = c & 63;
      float4 v = *reinterpret_cast<const float4*>(Ab + (size_t)row * HS + c4 * 4);
      union { unsigned short h[4]; unsigned long long u; } pk;
      pk.h[0] = f2bf(v.x); pk.h[1] = f2bf(v.y); pk.h[2] = f2bf(v.z); pk.h[3] = f2bf(v.w);
      int boff = row * 512 + ((c4 * 8) ^ ((row & 7) << 4));
      *reinterpret_cast<unsigned long long*>(reinterpret_cast<char*>(A_lds) + boff) = pk.u;
    }
    __syncthreads();

    // ---- GEMM1: H = relu(A @ W1[k] + b1[k]) ----
    f32x4 acc[4][4];
#pragma unroll
    for (int m = 0; m < 4; ++m)
#pragma unroll
      for (int n = 0; n < 4; ++n) acc[m][n] = zero4;

    const unsigned short* W1k = W1p + (size_t)k * 65536;
#pragma unroll
    for (int kk = 0; kk < 8; ++kk) {
      bf16x8 a[4], bbf[4];
#pragma unroll
      for (int m = 0; m < 4; ++m) {
        int r = m * 16 + l15;
        int boff = r * 512 + ((kk * 64 + l4 * 16) ^ ((r & 7) << 4));
        a[m] = *reinterpret_cast<const bf16x8*>(reinterpret_cast<const char*>(A_lds) + boff);
      }
#pragma unroll
      for (int n = 0; n < 4; ++n)
        bbf[n] = *reinterpret_cast<const bf16x8*>(W1k + ((size_t)(kk * 16 + nbase + n) * 64 + lane) * 8);
#pragma unroll
      for (int m = 0; m < 4; ++m)
#pragma unroll
        for (int n = 0; n < 4; ++n)
          acc[m][n] = __builtin_amdgcn_mfma_f32_16x16x32_bf16(a[m], bbf[n], acc[m][n], 0, 0, 0);
    }

    // ---- epilogue1: +b1, relu, -> H_lds (bf16, swizzled) ----
#pragma unroll
    for (int n = 0; n < 4; ++n) {
      int col = (nbase + n) * 16 + l15;
      float b1v = b1[k * HS + col];
#pragma unroll
      for (int m = 0; m < 4; ++m)
#pragma unroll
        for (int i = 0; i < 4; ++i) {
          float h = fmaxf(acc[m][n][i] + b1v, 0.f);
          int row = m * 16 + l4 * 4 + i;
          int boff = row * 512 + ((col * 2) ^ ((row & 7) << 4));
          *reinterpret_cast<unsigned short*>(reinterpret_cast<char*>(H_lds) + boff) = f2bf(h);
        }
    }
    __syncthreads();

    // ---- GEMM2: E = H @ W2[k] ----
#pragma unroll
    for (int m = 0; m < 4; ++m)
#pragma unroll
      for (int n = 0; n < 4; ++n) acc[m][n] = zero4;

    const unsigned short* W2k = W2p + (size_t)k * 65536;
#pragma unroll
    for (int kk = 0; kk < 8; ++kk) {
      bf16x8 a[4], bbf[4];
#pragma unroll
      for (int m = 0; m < 4; ++m) {
        int r = m * 16 + l15;
        int boff = r * 512 + ((kk * 64 + l4 * 16) ^ ((r & 7) << 4));
        a[m] = *reinterpret_cast<const bf16x8*>(reinterpret_cast<const char*>(H_lds) + boff);
      }
#pragma unroll
      for (int n = 0; n < 4; ++n)
        bbf[n] = *reinterpret_cast<const bf16x8*>(W2k + ((size_t)(kk * 16 + nbase + n) * 64 + lane) * 8);
#pragma unroll
      for (int m = 0; m < 4; ++m)
#pragma unroll
        for (int n = 0; n < 4; ++n)
          acc[m][n] = __builtin_amdgcn_mfma_f32_16x16x32_bf16(a[m], bbf[n], acc[m][n], 0, 0, 0);
    }

    // ---- weighted accumulate: out_acc += routing[b,k] * (E + b2[k]) ----
    float rw = routing[b * Kk + k];
#pragma unroll
    for (int n = 0; n < 4; ++n) {
      int col = (nbase + n) * 16 + l15;
      float b2v = b2[k * HS + col];
#pragma unroll
      for (int m = 0; m < 4; ++m)
#pragma unroll
        for (int i = 0; i < 4; ++i) out_acc[m][n][i] += rw * (acc[m][n][i] + b2v);
    }
  }  // k

  // ---- store fp32 ----
#pragma unroll
  for (int m = 0; m < 4; ++m)
#pragma unroll
    for (int i = 0; i < 4; ++i) {
      int row = m * 16 + l4 * 4 + i;
      float* orow = out + ((size_t)b * Ss + s0 + row) * HS;
#pragma unroll
      for (int n = 0; n < 4; ++n) orow[(nbase + n) * 16 + l15] = out_acc[m][n][i];
    }
}

extern "C" void kernel_launch(void* const* d_in, const int* in_sizes, int n_in,
                              void* d_out, int out_size, void* d_ws, size_t ws_size,
                              hipStream_t stream) {
  const float* rem = (const float*)d_in[0];
  const float* ret = (const float*)d_in[1];
  const float* Wr  = (const float*)d_in[2];
  const float* br  = (const float*)d_in[3];
  const float* Wt  = (const float*)d_in[4];
  const float* bt  = (const float*)d_in[5];
  const float* W1  = (const float*)d_in[6];
  const float* b1  = (const float*)d_in[7];
  const float* W2  = (const float*)d_in[8];
  const float* b2  = (const float*)d_in[9];
  float* out = (float*)d_out;

  char* w = (char*)d_ws;
  unsigned short* W1p = (unsigned short*)w;                     // 1 MB
  unsigned short* W2p = (unsigned short*)(w + (1u << 20));      // 1 MB
  float* sum_rem2 = (float*)(w + (2u << 20));                   // 64 KB
  float* sum_ret2 = (float*)(w + (2u << 20) + 65536);           // 512 KB
  float* routing  = (float*)(w + (2u << 20) + 65536 + 524288);  // 1 KB

  pack_w<<<256, 256, 0, stream>>>(W1, W1p);
  pack_w<<<256, 256, 0, stream>>>(W2, W2p);
  col_sums<<<Bb * (Kk + 1) * 2, 512, 0, stream>>>(rem, ret, sum_rem2, sum_ret2);
  routing_kernel<<<Bb, 256, 0, stream>>>(sum_rem2, sum_ret2, Wr, br, Wt, bt, routing);
  experts_kernel<<<Bb * 8, 256, 0, stream>>>(ret, W1p, W2p, b1, b2, routing, out);
}